// Round 3
// baseline (541.767 us; speedup 1.0000x reference)
//
#include <hip/hip_runtime.h>

// Fused 5x5 SAME conv + FastLIF + FastLI scan over T — FLOAT64 internal math.
// x: [T=256, 1, H=512, W=512] fp32, kernel: [1,1,5,5] fp32, out: [T,1,H,W] fp32.
//
// NUMERICS (unchanged from the passing R3/R4 kernels): conv accumulation +
// LIF/LI state all in double, identical per-pixel FMA ordering (kh 0..4,
// kw 0..4), inputs widened f32->f64 EXACTLY (at LDS read — same values
// bit-for-bit as widening at write), output rounded to f32 at store.
//
// R5/R6 (LDS-pipe bound per R4 post-mortem: VALUBusy 31%, HBM 26%, ~2350
// cyc/step vs ~400 cyc/SIMD of f64 FMA floor; LDS was ~240 ds_read_b64
// instrs/CU/step):
//   - LDS holds f32 (widening to f64 at read is exact) -> bytes halved
//   - thread = 1 row x 2 adjacent cols (even col base) -> 5 rows x 6 floats,
//     8B-aligned -> 3x ds_read_b64 per row = 15 read instrs per 2 px (was 30)
//   - output store = one aligned nontemporal 8B store (was 2x W-strided f32)
//   - R4 pipeline kept: register-staged prefetch 2 steps ahead, no-vmcnt-drain
//     barrier, t-loop unrolled by 2, statically named buffers/registers.
// R6 fix: __builtin_nontemporal_store needs a clang ext_vector, not HIP's
// float2 class — use float __attribute__((ext_vector_type(2))) throughout.

namespace {

typedef float f32x2 __attribute__((ext_vector_type(2)));

constexpr int T_STEPS = 256;
constexpr int H = 512;
constexpr int W = 512;
constexpr int HW = H * W;
constexpr int TW = 64;            // tile width
constexpr int TH = 8;             // tile height
constexpr int HALO_W = TW + 4;    // 68 (even -> row starts stay 8B-aligned)
constexpr int HALO_H = TH + 4;    // 12
constexpr int NLOAD = HALO_W * HALO_H;  // 816 floats per tile per timestep
constexpr int NTHREADS = 256;

__device__ __forceinline__ void sync_nodrain_vm() {
    // __syncthreads() would drain vmcnt(0) and kill the global prefetch
    // pipeline. We only need LDS visibility: drain lgkm (ds ops), barrier,
    // sched fences so nothing migrates across.
    __builtin_amdgcn_sched_barrier(0);
    asm volatile("s_waitcnt lgkmcnt(0)");
    __builtin_amdgcn_s_barrier();
    __builtin_amdgcn_sched_barrier(0);
}

__global__ __launch_bounds__(NTHREADS, 2)
void snn_fused(const float* __restrict__ x, const float* __restrict__ kern,
               float* __restrict__ out) {
    #pragma clang fp contract(off)

    __shared__ alignas(16) float smem[2][NLOAD];   // 2 x 816 x 4B = 6528 B

    const int tid = threadIdx.x;
    const int w0 = blockIdx.x * TW;
    const int h0 = blockIdx.y * TH;

    // 5x5 weights, widened to f64 (exact). Wave-uniform -> SGPR pairs.
    double wgt[25];
    #pragma unroll
    for (int i = 0; i < 25; ++i) wgt[i] = (double)kern[i];

    // Staging slots precomputed once; only the x base pointer moves per step.
    int  goff[4];
    bool gval[4];
    #pragma unroll
    for (int i = 0; i < 4; ++i) {
        int idx = tid + i * NTHREADS;
        int lhh = idx / HALO_W;
        int lww = idx - lhh * HALO_W;
        int gh = h0 - 2 + lhh;
        int gw = w0 - 2 + lww;
        goff[i] = gh * W + gw;
        gval[i] = (idx < NLOAD) &&
                  ((unsigned)gh < (unsigned)H) && ((unsigned)gw < (unsigned)W);
    }

    // One row, two adjacent columns per thread. Even column base -> the
    // 6-float window in halo coords starts at an even float index ->
    // 8B-aligned f32x2 reads.
    const int lwp = (tid & 31) * 2;       // 0,2,..,62
    const int lh  = tid >> 5;             // 0..7
    const int gh  = h0 + lh;
    const int gw  = w0 + lwp;

    double s1a = 0.0, s2a = 0.0;   // col gw
    double s1b = 0.0, s2b = 0.0;   // col gw+1

    // Prefetch register sets. OOB lanes are initialized to 0 and NEVER
    // overwritten (gval is loop-invariant), so the zero-halo comes for free.
    float rA[4], rB[4];
    #pragma unroll
    for (int i = 0; i < 4; ++i) { rA[i] = 0.0f; rB[i] = 0.0f; }

    // Issue 4 exec-masked global loads; no consumer here, so the compiler's
    // (counted) vmcnt wait lands at the much later stage_write.
    auto issue_loads = [&](int t, float* r) {
        const float* xt = x + (size_t)t * HW;
        #pragma unroll
        for (int i = 0; i < 4; ++i) {
            if (gval[i]) r[i] = xt[goff[i]];
        }
    };

    // Write the f32 registers to LDS (counted vmcnt wait inserted here).
    auto stage_write = [&](float* buf, const float* r) {
        #pragma unroll
        for (int i = 0; i < 4; ++i) {
            int idx = tid + i * NTHREADS;
            if (idx < NLOAD) buf[idx] = r[i];
        }
    };

    // 5x5 conv (two adjacent cols, f64 FMA, per-pixel accumulation order
    // IDENTICAL to the verified R3/R4 kernels) + LIF/LI + output store.
    auto step = [&](const float* buf, int t) {
        #pragma clang fp contract(off)
        // Output row lh needs halo rows lh..lh+4; output cols lwp,lwp+1 need
        // halo cols lwp..lwp+5 (6 floats, 8B-aligned at even lwp).
        const float* sm = buf + lh * HALO_W + lwp;
        double acc0 = 0.0, acc1 = 0.0;
        #pragma unroll
        for (int kh = 0; kh < 5; ++kh) {
            const f32x2* r2 = reinterpret_cast<const f32x2*>(sm + kh * HALO_W);
            f32x2 f0 = r2[0], f1 = r2[1], f2 = r2[2];
            double c0 = (double)f0.x, c1 = (double)f0.y;
            double c2 = (double)f1.x, c3 = (double)f1.y;
            double c4 = (double)f2.x, c5 = (double)f2.y;
            // Interleaved for ILP; each accumulator's own order unchanged.
            acc0 = __builtin_fma(wgt[kh * 5 + 0], c0, acc0);
            acc1 = __builtin_fma(wgt[kh * 5 + 0], c1, acc1);
            acc0 = __builtin_fma(wgt[kh * 5 + 1], c1, acc0);
            acc1 = __builtin_fma(wgt[kh * 5 + 1], c2, acc1);
            acc0 = __builtin_fma(wgt[kh * 5 + 2], c2, acc0);
            acc1 = __builtin_fma(wgt[kh * 5 + 2], c3, acc1);
            acc0 = __builtin_fma(wgt[kh * 5 + 3], c3, acc0);
            acc1 = __builtin_fma(wgt[kh * 5 + 3], c4, acc1);
            acc0 = __builtin_fma(wgt[kh * 5 + 4], c4, acc0);
            acc1 = __builtin_fma(wgt[kh * 5 + 4], c5, acc1);
        }

        {
            double v = 0.85 * s1a + acc0;
            double spk = (v >= 2.0) ? 1.0 : 0.0;
            s1a = v - spk * 2.0;
            s2a = 0.9 * s2a + spk;
        }
        {
            double v = 0.85 * s1b + acc1;
            double spk = (v >= 2.0) ? 1.0 : 0.0;
            s1b = v - spk * 2.0;
            s2b = 0.9 * s2b + spk;
        }

        f32x2 o;
        o.x = (float)s2a;
        o.y = (float)s2b;
        f32x2* outp = reinterpret_cast<f32x2*>(
            out + (size_t)t * HW + (size_t)gh * W + gw);
        __builtin_nontemporal_store(o, outp);
    };

    // ---- pipeline prologue: buf0 <- x[0]; x[1] left in flight in rB.
    issue_loads(0, rA);
    issue_loads(1, rB);
    stage_write(smem[0], rA);
    sync_nodrain_vm();

    // ---- steady state: 2 timesteps per iteration.
    // Invariant entering iter tb (t0 = 2*tb): smem[0] holds x[t0] (all waves,
    // barrier'd), rB holds x[t0+1] (in flight or arrived).
    for (int tb = 0; tb < 127; ++tb) {
        const int t0 = 2 * tb;

        // even timestep t0: compute from smem[0]
        issue_loads(t0 + 2, rA);        // ~1.5 iterations of latency slack
        step(smem[0], t0);
        stage_write(smem[1], rB);       // rB = x[t0+1]
        sync_nodrain_vm();

        // odd timestep t0+1: compute from smem[1]
        issue_loads(t0 + 3, rB);
        step(smem[1], t0 + 1);
        stage_write(smem[0], rA);       // rA = x[t0+2]
        sync_nodrain_vm();
    }

    // ---- tail: t = 254, 255 (no further prefetch)
    step(smem[0], 254);
    stage_write(smem[1], rB);           // rB = x[255]
    sync_nodrain_vm();
    step(smem[1], 255);
}

}  // namespace

extern "C" void kernel_launch(void* const* d_in, const int* in_sizes, int n_in,
                              void* d_out, int out_size, void* d_ws, size_t ws_size,
                              hipStream_t stream) {
    const float* x    = (const float*)d_in[0];
    const float* kern = (const float*)d_in[1];
    float* out        = (float*)d_out;

    dim3 grid(W / TW, H / TH);  // (8, 64) = 512 blocks -> 2 blocks/CU
    snn_fused<<<grid, dim3(NTHREADS), 0, stream>>>(x, kern, out);
}